// Round 3
// baseline (89.179 us; speedup 1.0000x reference)
//
#include <hip/hip_runtime.h>

// QSP via Laurent polynomial, SPLIT into two kernels (R13 = R12 + typo fix).
// Kernel 1 (1 wave) computes gamma_t from phis via the validated compressed
// recurrence and stores 64 float4 (1 KiB) into the harness workspace d_ws.
// Kernel 2 is a pure-FMA Horner in z=e^{2i theta}: no LDS, no barrier, no
// divergent setup -> removes 1024 redundant 127-step serial gamma chains and
// the 36-VGPR squeeze that exposed LDS latency per iteration (VALUBusy 27%).
// R13 delta vs R12: imag store slot 3 was oiv[7-3]=oiv[4] (typo) -> oiv[3].

#define NPHI 128

__device__ __forceinline__ float wave_shr1(float x) {
    // lane L <- lane L-1, lane 0 <- 0 (DPP wave_shr:1, bound_ctrl=1)
    return __builtin_bit_cast(float,
        __builtin_amdgcn_update_dpp(0, __builtin_bit_cast(int, x),
                                    0x138, 0xf, 0xf, true));
}

// ---------------- kernel 1: gamma coefficients (1 block, 1 wave) ------------
__global__ __launch_bounds__(64) void qsp_gamma(const float* __restrict__ phis,
                                                float4* __restrict__ gout)
{
    __shared__ float2 h[NPHI];                // 0.5 * e^{i phi_k}
    const int L = threadIdx.x;                // 0..63, single wave

    float sp, cp;
    __sincosf(phis[L], &sp, &cp);
    h[L] = make_float2(0.5f * cp, 0.5f * sp);
    __sincosf(phis[L + 64], &sp, &cp);
    h[L + 64] = make_float2(0.5f * cp, 0.5f * sp);
    // single wave: same-wave DS ordering makes reads below see these writes

    // lane L holds slots j=2L (A0/B0), j=2L+1 (A1/B1), scalar re/im
    float A0r = 0.f, A0i = 0.f, B0r = 0.f, B0i = 0.f;
    float A1r = 0.f, A1i = 0.f, B1r = 0.f, B1i = 0.f;
    const float2 h0 = h[0];
    if (L == 0) { A0r = 2.f * h0.x; A0i = 2.f * h0.y; }   // A[0] = e_0

    #pragma unroll 4
    for (int k = 1; k < NPHI; ++k) {
        const float2 hk = h[k];          // broadcast, off critical path
        const float hx = hk.x, hy = hk.y;
        // neighbor j-1 for slot0 = lane L-1's slot1 (DPP, lane0 -> 0)
        const float pAr = wave_shr1(A1r), pAi = wave_shr1(A1i);
        const float pBr = wave_shr1(B1r), pBi = wave_shr1(B1i);
        // butterflies (0.5 folded into h)
        const float u0r = pAr + pBr, u0i = pAi + pBi;
        const float v0r = A0r - B0r, v0i = A0i - B0i;
        const float sA0r = u0r + v0r, sA0i = u0i + v0i;
        const float sB0r = u0r - v0r, sB0i = u0i - v0i;
        const float u1r = A0r + B0r, u1i = A0i + B0i;
        const float v1r = A1r - B1r, v1i = A1i - B1i;
        const float sA1r = u1r + v1r, sA1i = u1i + v1i;
        const float sB1r = u1r - v1r, sB1i = u1i - v1i;
        // rotations: A <- e_k * sA ; B <- conj(e_k) * sB
        A0r = fmaf(hx, sA0r, -hy * sA0i);
        A0i = fmaf(hx, sA0i,  hy * sA0r);
        B0r = fmaf(hx, sB0r,  hy * sB0i);
        B0i = fmaf(hx, sB0i, -hy * sB0r);
        A1r = fmaf(hx, sA1r, -hy * sA1i);
        A1i = fmaf(hx, sA1i,  hy * sA1r);
        B1r = fmaf(hx, sB1r,  hy * sB1i);
        B1i = fmaf(hx, sB1i, -hy * sB1r);
    }
    gout[L] = make_float4(A0r, A0i, A1r, A1i);   // gamma_{2L}, gamma_{2L+1}
}

// ---------------- kernel 2: pure-FMA Horner over theta ----------------------
__global__ __launch_bounds__(256, 4) void qsp_main(
    const float* __restrict__ th,
    const float4* __restrict__ g4,   // 64 float4 of gamma pairs
    float* __restrict__ out,         // [0,B): real, [B,2B): imag
    int Bq8)                         // B/8
{
    const int tid = threadIdx.x;
    const int idx = blockIdx.x * blockDim.x + tid;
    const int lidx = (idx < Bq8) ? idx : 0;
    const float4 ta = ((const float4*)th)[2 * lidx];
    const float4 tb = ((const float4*)th)[2 * lidx + 1];
    const float th8[8] = {ta.x, ta.y, ta.z, ta.w, tb.x, tb.y, tb.z, tb.w};

    float zr[8], zi[8];
    #pragma unroll
    for (int e = 0; e < 8; ++e) {
        float s, c;
        __sincosf(2.f * th8[e], &s, &c);
        zr[e] = c; zi[e] = s;
    }

    float ar[8], ai[8];
    #pragma unroll
    for (int e = 0; e < 8; ++e) { ar[e] = 0.f; ai[e] = 0.f; }

    // t descending from 127; pair (gA,gB) covers t = 2jj+3 .. 2jj
    float4 gA = g4[62];
    float4 gB = g4[63];

    #define QSP_STEP(gr, gi)                                                  \
        _Pragma("unroll")                                                     \
        for (int e = 0; e < 8; ++e) {                                         \
            const float nr = fmaf(ar[e], zr[e], fmaf(-ai[e], zi[e], (gr)));   \
            const float ni = fmaf(ar[e], zi[e], fmaf( ai[e], zr[e], (gi)));   \
            ar[e] = nr; ai[e] = ni;                                           \
        }

    #pragma unroll 1
    for (int jj = 62; jj >= 2; jj -= 2) {
        const float4 nA = g4[jj - 2];    // prefetch next pair group
        const float4 nB = g4[jj - 1];
        __builtin_amdgcn_sched_barrier(0);   // pin: loads issue before FMAs
        QSP_STEP(gB.z, gB.w)             // t = 2jj+3
        QSP_STEP(gB.x, gB.y)             // t = 2jj+2
        QSP_STEP(gA.z, gA.w)             // t = 2jj+1
        QSP_STEP(gA.x, gA.y)             // t = 2jj
        gA = nA; gB = nB;
    }
    QSP_STEP(gB.z, gB.w)                 // t = 3
    QSP_STEP(gB.x, gB.y)                 // t = 2
    QSP_STEP(gA.z, gA.w)                 // t = 1
    QSP_STEP(gA.x, gA.y)                 // t = 0
    #undef QSP_STEP

    // multiply by e^{-127 i theta}: re = ar*C + ai*S, im = ai*C - ar*S
    float orv[8], oiv[8];
    #pragma unroll
    for (int e = 0; e < 8; ++e) {
        float S, C;
        __sincosf(127.f * th8[e], &S, &C);
        orv[e] = fmaf(ar[e], C,  ai[e] * S);
        oiv[e] = fmaf(ai[e], C, -ar[e] * S);
    }

    if (idx < Bq8) {
        float4* o4 = (float4*)out;
        const int ib = 2 * Bq8;   // imag base in float4 units (= B/4)
        o4[2 * idx]          = make_float4(orv[0], orv[1], orv[2], orv[3]);
        o4[2 * idx + 1]      = make_float4(orv[4], orv[5], orv[6], orv[7]);
        o4[ib + 2 * idx]     = make_float4(oiv[0], oiv[1], oiv[2], oiv[3]);
        o4[ib + 2 * idx + 1] = make_float4(oiv[4], oiv[5], oiv[6], oiv[7]);
    }
}

extern "C" void kernel_launch(void* const* d_in, const int* in_sizes, int n_in,
                              void* d_out, int out_size, void* d_ws, size_t ws_size,
                              hipStream_t stream)
{
    const float* th   = (const float*)d_in[0];
    const float* phis = (const float*)d_in[1];
    float* out = (float*)d_out;
    const int B = in_sizes[0];          // 2097152
    const int Bq8 = B >> 3;             // 262144 threads
    const int block = 256;              // 4 waves
    const int grid = (Bq8 + block - 1) / block;   // 1024 blocks = 4/CU

    float4* gbuf = (float4*)d_ws;       // 1 KiB of workspace for gamma pairs

    qsp_gamma<<<1, 64, 0, stream>>>(phis, gbuf);
    qsp_main<<<grid, block, 0, stream>>>(th, gbuf, out, Bq8);
}